// Round 6
// baseline (664.352 us; speedup 1.0000x reference)
//
#include <hip/hip_runtime.h>
#include <hip/hip_bf16.h>

#define TT 2048
#define BB 512
#define HH 32
#define NPAIR (TT * BB)
#define PSTRIDE (BB * HH)   // elements per t-slice of P = 16384
#define CSC 2.88539008177792681f   // 2*log2(e), folded into W/b/P

// Pin a value into a live VGPR (R9-proven variant, no memory clobber).
#define PIN(x) asm volatile("" : "+v"(x))

#if defined(__has_builtin)
#  if __has_builtin(__builtin_amdgcn_permlane16_swap)
#    define HAVE_PL16 1
#  endif
#  if __has_builtin(__builtin_amdgcn_permlane32_swap)
#    define HAVE_PL32 1
#  endif
#endif
#ifndef HAVE_PL16
#  define HAVE_PL16 0
#endif
#ifndef HAVE_PL32
#  define HAVE_PL32 0
#endif

// Unscaled tanh for the fallback kernel.
__device__ __forceinline__ float fast_tanh(float u) {
    float e = exp2f(u * CSC);
    return fmaf(__builtin_amdgcn_rcpf(e + 1.0f), -2.0f, 1.0f);
}

// DPP row-rotate by N within each 16-lane row (direct ROW_ROR:N, N=1..15).
template <int N>
__device__ __forceinline__ float dpp_ror(float v) {
    return __int_as_float(__builtin_amdgcn_mov_dpp(
        __float_as_int(v), 0x120 | N, 0xF, 0xF, false));
}
// lane xor 16 within each 32-lane group (BitMode: xor=16, and=0x1F). Fallback only.
__device__ __forceinline__ float swz_x16(float v) {
    return __int_as_float(__builtin_amdgcn_ds_swizzle(__float_as_int(v), 0x401F));
}

__device__ __forceinline__ unsigned short f2bfu(float f) {
    __hip_bfloat16 h = __float2bfloat16(f);
    return *reinterpret_cast<unsigned short*>(&h);
}
__device__ __forceinline__ short f2bf(float f) {
    __hip_bfloat16 h = __float2bfloat16(f);
    return *reinterpret_cast<short*>(&h);
}

typedef __attribute__((ext_vector_type(8))) short bf16x8;
typedef __attribute__((ext_vector_type(4))) float f32x4;

// ---------------- Pass 1: MFMA precompute, swapped operands, 64 pairs/wave -------------
__global__ __launch_bounds__(256) void precompute_mfma2(
        const int* __restrict__ x, const float* __restrict__ emb,
        const float* __restrict__ W_rnn, const float* __restrict__ b_rnn,
        __hip_bfloat16* __restrict__ P) {
    const int l  = threadIdx.x & 63;
    const int wv = (blockIdx.x * 256 + threadIdx.x) >> 6;   // global wave id
    const int m16 = l & 15;
    const int q   = l >> 4;           // quad: k-slice base q*8, C-row base q*4
    const int pair0 = wv * 64;

    bf16x8 a0, a1;
#pragma unroll
    for (int j = 0; j < 8; ++j) {
        a0[j] = f2bf(CSC * W_rnn[(q * 8 + j) * HH + m16]);
        a1[j] = f2bf(CSC * W_rnn[(q * 8 + j) * HH + m16 + 16]);
    }
    f32x4 cb0, cb1;
#pragma unroll
    for (int reg = 0; reg < 4; ++reg) {
        cb0[reg] = CSC * b_rnn[q * 4 + reg];
        cb1[reg] = CSC * b_rnn[q * 4 + reg + 16];
    }

#pragma unroll
    for (int it = 0; it < 4; ++it) {
        const int pairB = pair0 + it * 16;
        const int idx = x[pairB + m16];
        const float4* ep = (const float4*)(emb + (size_t)idx * HH + q * 8);
        float4 e0 = ep[0], e1 = ep[1];
        bf16x8 bf;
        bf[0] = f2bf(e0.x); bf[1] = f2bf(e0.y); bf[2] = f2bf(e0.z); bf[3] = f2bf(e0.w);
        bf[4] = f2bf(e1.x); bf[5] = f2bf(e1.y); bf[6] = f2bf(e1.z); bf[7] = f2bf(e1.w);

        f32x4 c0 = cb0, c1 = cb1;
        c0 = __builtin_amdgcn_mfma_f32_16x16x32_bf16(a0, bf, c0, 0, 0, 0);
        c1 = __builtin_amdgcn_mfma_f32_16x16x32_bf16(a1, bf, c1, 0, 0, 0);

        uint2 s0, s1;
        s0.x = (unsigned)f2bfu(c0[0]) | ((unsigned)f2bfu(c0[1]) << 16);
        s0.y = (unsigned)f2bfu(c0[2]) | ((unsigned)f2bfu(c0[3]) << 16);
        s1.x = (unsigned)f2bfu(c1[0]) | ((unsigned)f2bfu(c1[1]) << 16);
        s1.y = (unsigned)f2bfu(c1[2]) | ((unsigned)f2bfu(c1[3]) << 16);
        __hip_bfloat16* pp = P + (size_t)(pairB + m16) * HH + q * 4;
        *(uint2*)(pp)      = s0;
        *(uint2*)(pp + 16) = s1;
    }
}

// ---------------- Pass 2: v18 — 4-way k-split, one row per 64-lane wave ---------------
// Lanes: i = l&15, g = l>>4. Each lane computes ONE 16-term partial (j, k-half):
// 16 FMAs/step vs v14's 32, rotations unchanged (15). Grid stays 512 waves (1 row ea).
// State r = rcp(1+2^u) (v15-validated -2 weight fold + rowsum constant on p).
// Layout A (even t): g0:r_lo, g1:r_hi, g2:r_lo, g3:r_hi. Even-step pairs ^16
// (permlane16_swap): (g0,g1)->u_i, (g2,g3)->u_{16+i} => Layout B {lo,lo,hi,hi}.
// Odd-step pairs ^32 (permlane32_swap): (g0,g2)->u_i, (g1,g3)->u_{16+i} => Layout A.
// Alternating primitives make the state layout self-restoring: NO fix-up ops.
// p + rowsum folded only on the k-low lane of each pair (avoids double count) via a
// loop-invariant per-lane (mult, bias) pair -> 1 off-chain fma.
__global__ __launch_bounds__(64, 1) void rnn_seq_v18(
        const __hip_bfloat16* __restrict__ P, const float* __restrict__ W_rnn,
        const float* __restrict__ W_cls, const float* __restrict__ b_cls,
        float* __restrict__ out) {
    const int l = threadIdx.x;
    const int i = l & 15;
    const int g = l >> 4;

    // Direction probe (validated R6-R17: absmax 0.0).
    int rt = __builtin_amdgcn_mov_dpp(i, 0x121, 0xF, 0xF, false);
    const int d = (rt == ((i + 1) & 15)) ? 1 : -1;

#if HAVE_PL16
    bool takeX16;
    {
        unsigned lv = (unsigned)l;
        auto pr = __builtin_amdgcn_permlane16_swap(lv, lv, false, false);
        takeX16 = ((unsigned)pr[0] == (unsigned)(l ^ 16));
    }
#endif
#if HAVE_PL32
    bool takeX32;
    {
        unsigned lv = (unsigned)l;
        auto pr = __builtin_amdgcn_permlane32_swap(lv, lv, false, false);
        takeX32 = ((unsigned)pr[0] == (unsigned)(l ^ 32));
    }
#endif

    // Roles. heldE/heldO: which k-half this lane's group holds at even/odd steps.
    const int heldE = g & 1;          // layout A: g0 lo, g1 hi, g2 lo, g3 hi
    const int heldO = g >> 1;         // layout B: g0 lo, g1 lo, g2 hi, g3 hi
    const int jE = (g >> 1) * 16 + i; // even-step target unit
    const int jO = (g & 1) * 16 + i;  // odd-step target unit

    // Weights: wP[o] pairs with rot_o(r) -> k = heldP*16 + ((i+d*o)&15), j = jP.
    float wE[16], wO[16];
#pragma unroll
    for (int o = 0; o < 16; ++o) {
        const int kk = (i + d * o) & 15;
        wE[o] = -2.0f * CSC * W_rnn[(HH + heldE * 16 + kk) * HH + jE];
        wO[o] = -2.0f * CSC * W_rnn[(HH + heldO * 16 + kk) * HH + jO];
    }
#pragma unroll
    for (int o = 0; o < 16; ++o) { PIN(wE[o]); PIN(wO[o]); }

    // Rowsum constants (h = 1-2r fold). Folded ONLY on the k-low lane of each pair.
    float WSE = 0.0f, WSO = 0.0f;
#pragma unroll
    for (int k = 0; k < HH; ++k) {
        WSE += W_rnn[(HH + k) * HH + jE];
        WSO += W_rnn[(HH + k) * HH + jO];
    }
    const float mEf  = (heldE == 0) ? 1.0f : 0.0f;
    const float wsbE = (heldE == 0) ? CSC * WSE : 0.0f;
    const float mOf  = (heldO == 0) ? 1.0f : 0.0f;
    const float wsbO = (heldO == 0) ? CSC * WSO : 0.0f;

    const int row = blockIdx.x;
    const __hip_bfloat16* gpE = P + (size_t)row * HH + jE;
    const __hip_bfloat16* gpO = P + (size_t)row * HH + jO;

    // Per 8-t half-batch: 4 even + 4 odd p values.
    float peA[4], poA[4], peB[4], poB[4];
#pragma unroll
    for (int s = 0; s < 4; ++s) {
        peA[s] = __bfloat162float(gpE[(size_t)(2 * s) * PSTRIDE]);
        poA[s] = __bfloat162float(gpO[(size_t)(2 * s + 1) * PSTRIDE]);
    }

    float r = 0.5f;   // h0 = 0 => r0 = 0.5 (layout-agnostic)

    auto stepE = [&](float pld) {
        float p_eff = fmaf(pld, mEf, wsbE);
        float rot[16];
        rot[0] = r;
        rot[1]  = dpp_ror<1>(r);  rot[2]  = dpp_ror<2>(r);  rot[3]  = dpp_ror<3>(r);
        rot[4]  = dpp_ror<4>(r);  rot[5]  = dpp_ror<5>(r);  rot[6]  = dpp_ror<6>(r);
        rot[7]  = dpp_ror<7>(r);  rot[8]  = dpp_ror<8>(r);  rot[9]  = dpp_ror<9>(r);
        rot[10] = dpp_ror<10>(r); rot[11] = dpp_ror<11>(r); rot[12] = dpp_ror<12>(r);
        rot[13] = dpp_ror<13>(r); rot[14] = dpp_ror<14>(r); rot[15] = dpp_ror<15>(r);
        float c0 = fmaf(rot[0], wE[0], p_eff);
        float c1 = rot[1] * wE[1], c2 = rot[2] * wE[2], c3 = rot[3] * wE[3];
#pragma unroll
        for (int m = 1; m < 4; ++m) {
            c0 = fmaf(rot[4*m+0], wE[4*m+0], c0);
            c1 = fmaf(rot[4*m+1], wE[4*m+1], c1);
            c2 = fmaf(rot[4*m+2], wE[4*m+2], c2);
            c3 = fmaf(rot[4*m+3], wE[4*m+3], c3);
        }
        float own = (c0 + c1) + (c2 + c3);
#if HAVE_PL16
        unsigned sv = __float_as_uint(own);
        auto sw = __builtin_amdgcn_permlane16_swap(sv, sv, false, false);
        float recv = takeX16 ? __uint_as_float((unsigned)sw[0])
                             : __uint_as_float((unsigned)sw[1]);
#else
        float recv = swz_x16(own);
#endif
        float u = own + recv;
        float e = exp2f(u);
        r = __builtin_amdgcn_rcpf(e + 1.0f);
    };

    auto stepO = [&](float pld) {
        float p_eff = fmaf(pld, mOf, wsbO);
        float rot[16];
        rot[0] = r;
        rot[1]  = dpp_ror<1>(r);  rot[2]  = dpp_ror<2>(r);  rot[3]  = dpp_ror<3>(r);
        rot[4]  = dpp_ror<4>(r);  rot[5]  = dpp_ror<5>(r);  rot[6]  = dpp_ror<6>(r);
        rot[7]  = dpp_ror<7>(r);  rot[8]  = dpp_ror<8>(r);  rot[9]  = dpp_ror<9>(r);
        rot[10] = dpp_ror<10>(r); rot[11] = dpp_ror<11>(r); rot[12] = dpp_ror<12>(r);
        rot[13] = dpp_ror<13>(r); rot[14] = dpp_ror<14>(r); rot[15] = dpp_ror<15>(r);
        float c0 = fmaf(rot[0], wO[0], p_eff);
        float c1 = rot[1] * wO[1], c2 = rot[2] * wO[2], c3 = rot[3] * wO[3];
#pragma unroll
        for (int m = 1; m < 4; ++m) {
            c0 = fmaf(rot[4*m+0], wO[4*m+0], c0);
            c1 = fmaf(rot[4*m+1], wO[4*m+1], c1);
            c2 = fmaf(rot[4*m+2], wO[4*m+2], c2);
            c3 = fmaf(rot[4*m+3], wO[4*m+3], c3);
        }
        float own = (c0 + c1) + (c2 + c3);
#if HAVE_PL32
        unsigned sv = __float_as_uint(own);
        auto sw = __builtin_amdgcn_permlane32_swap(sv, sv, false, false);
        float recv = takeX32 ? __uint_as_float((unsigned)sw[0])
                             : __uint_as_float((unsigned)sw[1]);
#else
        float recv = __shfl_xor(own, 32, 64);
#endif
        float u = own + recv;
        float e = exp2f(u);
        r = __builtin_amdgcn_rcpf(e + 1.0f);
    };

#pragma unroll 1
    for (int e = 0; e < TT / 16; ++e) {
        const int tB = e * 16 + 8;
#pragma unroll
        for (int s = 0; s < 4; ++s) {
            peB[s] = __bfloat162float(gpE[(size_t)(tB + 2 * s) * PSTRIDE]);
            poB[s] = __bfloat162float(gpO[(size_t)(tB + 2 * s + 1) * PSTRIDE]);
        }
#pragma unroll
        for (int s = 0; s < 4; ++s) { PIN(peA[s]); PIN(poA[s]); }
#pragma unroll
        for (int s = 0; s < 4; ++s) { stepE(peA[s]); stepO(poA[s]); }

        int tA = e * 16 + 16;
        if (tA > TT - 8) tA = TT - 8;
#pragma unroll
        for (int s = 0; s < 4; ++s) {
            peA[s] = __bfloat162float(gpE[(size_t)(tA + 2 * s) * PSTRIDE]);
            poA[s] = __bfloat162float(gpO[(size_t)(tA + 2 * s + 1) * PSTRIDE]);
        }
#pragma unroll
        for (int s = 0; s < 4; ++s) { PIN(peB[s]); PIN(poB[s]); }
#pragma unroll
        for (int s = 0; s < 4; ++s) { stepE(peB[s]); stepO(poB[s]); }
    }

    // Final state is Layout A: lanes 0-31 hold r_j at lane j (g0: j=i, g1: j=16+i).
    __shared__ float hf[32];
    if (l < 32) hf[l] = fmaf(r, -2.0f, 1.0f);   // h = 1 - 2r (single wave: no barrier)
    if (l < 5) {
        float acc = b_cls[l];
#pragma unroll
        for (int k = 0; k < 32; ++k)
            acc = fmaf(hf[k], W_cls[k * 5 + l], acc);
        out[row * 5 + l] = acc;
    }
}

// ---------------- Fallback (fused) for tiny workspace ----------------------------------
__device__ __forceinline__ float rnn_step_fb(const float4 xt[8], const float wx[32],
                                             const float wh[32], float bj,
                                             float* hrow, int lane) {
    float u0 = 0.f, u1 = 0.f, u2 = 0.f, u3 = 0.f;
#pragma unroll
    for (int q = 0; q < 8; ++q) {
        u0 = fmaf(xt[q].x, wx[4*q+0], u0);
        u1 = fmaf(xt[q].y, wx[4*q+1], u1);
        u2 = fmaf(xt[q].z, wx[4*q+2], u2);
        u3 = fmaf(xt[q].w, wx[4*q+3], u3);
    }
    const float4* hp = (const float4*)hrow;
#pragma unroll
    for (int q = 0; q < 8; ++q) {
        float4 hv = hp[q];
        u0 = fmaf(hv.x, wh[4*q+0], u0);
        u1 = fmaf(hv.y, wh[4*q+1], u1);
        u2 = fmaf(hv.z, wh[4*q+2], u2);
        u3 = fmaf(hv.w, wh[4*q+3], u3);
    }
    float hn = fast_tanh(bj + ((u0 + u1) + (u2 + u3)));
    hrow[lane] = hn;
    return hn;
}

__global__ __launch_bounds__(64, 1) void rnn_seq_kernel(
        const int* __restrict__ x, const float* __restrict__ emb,
        const float* __restrict__ W_rnn, const float* __restrict__ b_rnn,
        const float* __restrict__ W_cls, const float* __restrict__ b_cls,
        float* __restrict__ out) {
    const int lane = threadIdx.x & 31;
    const int grp  = threadIdx.x >> 5;
    const int row  = blockIdx.x * 2 + grp;
    __shared__ float hbuf[2][HH];
    float wx[32], wh[32];
#pragma unroll
    for (int k = 0; k < 32; ++k) {
        wx[k] = W_rnn[k * HH + lane];
        wh[k] = W_rnn[(HH + k) * HH + lane];
    }
    const float bj = b_rnn[lane];
    hbuf[grp][lane] = 0.0f;
    float* hrow = &hbuf[grp][0];
    int i1 = x[1 * BB + row];
    float4 xcur[8], xnxt[8];
    {
        int i0 = x[0 * BB + row];
        const float4* ep = (const float4*)(emb + (size_t)i0 * HH);
#pragma unroll
        for (int q = 0; q < 8; ++q) xcur[q] = ep[q];
    }
    for (int t = 0; t < TT; t += 2) {
        int i2 = x[min(t + 2, TT - 1) * BB + row];
        {
            const float4* ep = (const float4*)(emb + (size_t)i1 * HH);
#pragma unroll
            for (int q = 0; q < 8; ++q) xnxt[q] = ep[q];
        }
        rnn_step_fb(xcur, wx, wh, bj, hrow, lane);
        i1 = x[min(t + 3, TT - 1) * BB + row];
        {
            const float4* ep = (const float4*)(emb + (size_t)i2 * HH);
#pragma unroll
            for (int q = 0; q < 8; ++q) xcur[q] = ep[q];
        }
        rnn_step_fb(xnxt, wx, wh, bj, hrow, lane);
    }
    if (lane < 5) {
        float acc = b_cls[lane];
#pragma unroll
        for (int k = 0; k < 32; ++k)
            acc = fmaf(hrow[k], W_cls[k * 5 + lane], acc);
        out[row * 5 + lane] = acc;
    }
}

extern "C" void kernel_launch(void* const* d_in, const int* in_sizes, int n_in,
                              void* d_out, int out_size, void* d_ws, size_t ws_size,
                              hipStream_t stream) {
    const int*   x     = (const int*)d_in[0];
    const float* emb   = (const float*)d_in[1];
    const float* W_rnn = (const float*)d_in[2];
    const float* b_rnn = (const float*)d_in[3];
    const float* W_cls = (const float*)d_in[4];
    const float* b_cls = (const float*)d_in[5];
    float* out = (float*)d_out;

    const size_t need16 = (size_t)NPAIR * HH * 2;   // 64 MiB (bf16 P)
    if (ws_size >= need16) {
        __hip_bfloat16* P = (__hip_bfloat16*)d_ws;
        const int pre_blocks = NPAIR / 256;         // 4096 blocks x 4 waves x 64 pairs
        precompute_mfma2<<<pre_blocks, 256, 0, stream>>>(x, emb, W_rnn, b_rnn, P);
        rnn_seq_v18<<<BB, 64, 0, stream>>>(P, W_rnn, W_cls, b_cls, out);
    } else {
        rnn_seq_kernel<<<BB / 2, 64, 0, stream>>>(x, emb, W_rnn, b_rnn, W_cls, b_cls, out);
    }
}

// Round 7
// 359.540 us; speedup vs baseline: 1.8478x; 1.8478x over previous
//
#include <hip/hip_runtime.h>
#include <hip/hip_bf16.h>

#define TT 2048
#define BB 512
#define HH 32
#define NPAIR (TT * BB)
#define PSTRIDE (BB * HH)   // elements per t-slice of P = 16384
#define CSC 2.88539008177792681f   // 2*log2(e), folded into W/b/P

// Pin a value into a live VGPR (R9-proven variant, no memory clobber).
#define PIN(x) asm volatile("" : "+v"(x))

#if defined(__has_builtin)
#  if __has_builtin(__builtin_amdgcn_permlane16_swap)
#    define HAVE_PLSWAP 1
#  endif
#endif
#ifndef HAVE_PLSWAP
#  define HAVE_PLSWAP 0
#endif

typedef __attribute__((ext_vector_type(2))) float f32x2;

// Inputs pre-scaled by CSC => tanh(u) = 1 - 2/(1+2^u'), u' = CSC*u arrives ready.
__device__ __forceinline__ float fast_tanh_pre(float u) {
    float e = exp2f(u);
    return fmaf(__builtin_amdgcn_rcpf(e + 1.0f), -2.0f, 1.0f);
}
// Unscaled variant for the fallback kernel.
__device__ __forceinline__ float fast_tanh(float u) {
    float e = exp2f(u * CSC);
    return fmaf(__builtin_amdgcn_rcpf(e + 1.0f), -2.0f, 1.0f);
}

// DPP row-rotate by N within each 16-lane row (direct ROW_ROR:N, N=1..15).
template <int N>
__device__ __forceinline__ float dpp_ror(float v) {
    return __int_as_float(__builtin_amdgcn_mov_dpp(
        __float_as_int(v), 0x120 | N, 0xF, 0xF, false));
}
// Rotation packaged as the LO half of a 64-bit pair (HI undef — never read: the
// pk ops below use op_sel to replicate src0.LO into both output halves).
template <int N>
__device__ __forceinline__ f32x2 dpp_ror_p(float v) {
    f32x2 r;
    r.x = dpp_ror<N>(v);
    return r;
}
// lane xor 16 within each 32-lane group (BitMode: xor=16, and=0x1F). Fallback only.
__device__ __forceinline__ float swz_x16(float v) {
    return __int_as_float(__builtin_amdgcn_ds_swizzle(__float_as_int(v), 0x401F));
}

// Packed f32 MAC pair: out.lo = rot.lo*w.lo (+acc.lo), out.hi = rot.lo*w.hi (+acc.hi).
// src0.LO replicated to both halves via op_sel_hi[0]=0 — one instruction computes the
// keep-side AND send-side term for one rotation (v19's single change vs v14).
#define PKMUL(dst, rp, w) \
    asm("v_pk_mul_f32 %0, %1, %2 op_sel:[0,0] op_sel_hi:[0,1]" \
        : "=v"(dst) : "v"(rp), "v"(w))
#define PKFMA(acc, rp, w) \
    asm("v_pk_fma_f32 %0, %1, %2, %0 op_sel:[0,0,0] op_sel_hi:[0,1,1]" \
        : "+v"(acc) : "v"(rp), "v"(w))

__device__ __forceinline__ unsigned short f2bfu(float f) {
    __hip_bfloat16 h = __float2bfloat16(f);
    return *reinterpret_cast<unsigned short*>(&h);
}
__device__ __forceinline__ short f2bf(float f) {
    __hip_bfloat16 h = __float2bfloat16(f);
    return *reinterpret_cast<short*>(&h);
}

typedef __attribute__((ext_vector_type(8))) short bf16x8;
typedef __attribute__((ext_vector_type(4))) float f32x4;

// ---------------- Pass 1: MFMA precompute, swapped operands, 64 pairs/wave -------------
__global__ __launch_bounds__(256) void precompute_mfma2(
        const int* __restrict__ x, const float* __restrict__ emb,
        const float* __restrict__ W_rnn, const float* __restrict__ b_rnn,
        __hip_bfloat16* __restrict__ P) {
    const int l  = threadIdx.x & 63;
    const int wv = (blockIdx.x * 256 + threadIdx.x) >> 6;   // global wave id
    const int m16 = l & 15;
    const int q   = l >> 4;           // quad: k-slice base q*8, C-row base q*4
    const int pair0 = wv * 64;

    bf16x8 a0, a1;
#pragma unroll
    for (int j = 0; j < 8; ++j) {
        a0[j] = f2bf(CSC * W_rnn[(q * 8 + j) * HH + m16]);
        a1[j] = f2bf(CSC * W_rnn[(q * 8 + j) * HH + m16 + 16]);
    }
    f32x4 cb0, cb1;
#pragma unroll
    for (int reg = 0; reg < 4; ++reg) {
        cb0[reg] = CSC * b_rnn[q * 4 + reg];
        cb1[reg] = CSC * b_rnn[q * 4 + reg + 16];
    }

#pragma unroll
    for (int it = 0; it < 4; ++it) {
        const int pairB = pair0 + it * 16;
        const int idx = x[pairB + m16];
        const float4* ep = (const float4*)(emb + (size_t)idx * HH + q * 8);
        float4 e0 = ep[0], e1 = ep[1];
        bf16x8 bf;
        bf[0] = f2bf(e0.x); bf[1] = f2bf(e0.y); bf[2] = f2bf(e0.z); bf[3] = f2bf(e0.w);
        bf[4] = f2bf(e1.x); bf[5] = f2bf(e1.y); bf[6] = f2bf(e1.z); bf[7] = f2bf(e1.w);

        f32x4 c0 = cb0, c1 = cb1;
        c0 = __builtin_amdgcn_mfma_f32_16x16x32_bf16(a0, bf, c0, 0, 0, 0);
        c1 = __builtin_amdgcn_mfma_f32_16x16x32_bf16(a1, bf, c1, 0, 0, 0);

        uint2 s0, s1;
        s0.x = (unsigned)f2bfu(c0[0]) | ((unsigned)f2bfu(c0[1]) << 16);
        s0.y = (unsigned)f2bfu(c0[2]) | ((unsigned)f2bfu(c0[3]) << 16);
        s1.x = (unsigned)f2bfu(c1[0]) | ((unsigned)f2bfu(c1[1]) << 16);
        s1.y = (unsigned)f2bfu(c1[2]) | ((unsigned)f2bfu(c1[3]) << 16);
        __hip_bfloat16* pp = P + (size_t)(pairB + m16) * HH + q * 4;
        *(uint2*)(pp)      = s0;
        *(uint2*)(pp + 16) = s1;
    }
}

// ---------------- Pass 2: v19 = v14 structure, keep/send packed into v_pk_fma_f32 ------
// Per-wave issue cadence is ~5.3 cyc/instr at 1 wave/SIMD (R2-R6 fit), so the only
// lever is instrs/step: 32 FMA -> 16 pk_fma (op_sel-replicated rot), 6 adds -> 3
// pk_add. Everything else (layout, probes, prefetch, epilogue) is v14-identical.
__global__ __launch_bounds__(64, 1) void rnn_seq_v19(
        const __hip_bfloat16* __restrict__ P, const float* __restrict__ W_rnn,
        const float* __restrict__ W_cls, const float* __restrict__ b_cls,
        float* __restrict__ out) {
    const int l = threadIdx.x;
    const int i = l & 15;
    const int q = (l >> 4) & 1;

    // Direction probe (validated R6-R18: absmax 0.0).
    int rt = __builtin_amdgcn_mov_dpp(i, 0x121, 0xF, 0xF, false);
    const int d = (rt == ((i + 1) & 15)) ? 1 : -1;

#if HAVE_PLSWAP
    // Output-order probe for permlane16_swap (per-lane select; HW-validated in v14).
    bool takeX;
    {
        unsigned lv = (unsigned)l;
        auto pr = __builtin_amdgcn_permlane16_swap(lv, lv, false, false);
        takeX = ((unsigned)pr[0] == (unsigned)(l ^ 16));
    }
#endif

    // Weight pairs: wKS[o] = (wKeep[o], wSend[o]). Same live size as v14 (32 VGPRs).
    f32x2 wKS[16];
#pragma unroll
    for (int o = 0; o < 16; ++o) {
        const int k = q * 16 + ((i + d * o) & 15);
        wKS[o].x = CSC * W_rnn[(HH + k) * HH + (q * 16 + i)];
        wKS[o].y = CSC * W_rnn[(HH + k) * HH + ((q ^ 1) * 16 + i)];
    }
#pragma unroll
    for (int o = 0; o < 16; ++o) PIN(wKS[o]);

    const __hip_bfloat16* gp = P + (size_t)blockIdx.x * 64 + l;

    float pA[8], pB[8];
#pragma unroll
    for (int t = 0; t < 8; ++t)
        pA[t] = __bfloat162float(gp[(size_t)t * PSTRIDE]);

    float h = 0.0f;

    auto step = [&](float p) {
        f32x2 h_p; h_p.x = h;                 // rot(0); HI undef, never read (op_sel)
        f32x2 r1  = dpp_ror_p<1>(h),  r2  = dpp_ror_p<2>(h),  r3  = dpp_ror_p<3>(h);
        f32x2 r4  = dpp_ror_p<4>(h),  r5  = dpp_ror_p<5>(h),  r6  = dpp_ror_p<6>(h);
        f32x2 r7  = dpp_ror_p<7>(h),  r8  = dpp_ror_p<8>(h),  r9  = dpp_ror_p<9>(h);
        f32x2 r10 = dpp_ror_p<10>(h), r11 = dpp_ror_p<11>(h), r12 = dpp_ror_p<12>(h);
        f32x2 r13 = dpp_ror_p<13>(h), r14 = dpp_ror_p<14>(h), r15 = dpp_ror_p<15>(h);

        f32x2 a0, a1, a2, a3;   // .x accumulates keep, .y accumulates send
        PKMUL(a0, h_p, wKS[0]);
        PKMUL(a1, r1,  wKS[1]);
        PKMUL(a2, r2,  wKS[2]);
        PKMUL(a3, r3,  wKS[3]);
        PKFMA(a0, r4,  wKS[4]);  PKFMA(a1, r5,  wKS[5]);
        PKFMA(a2, r6,  wKS[6]);  PKFMA(a3, r7,  wKS[7]);
        PKFMA(a0, r8,  wKS[8]);  PKFMA(a1, r9,  wKS[9]);
        PKFMA(a2, r10, wKS[10]); PKFMA(a3, r11, wKS[11]);
        PKFMA(a0, r12, wKS[12]); PKFMA(a1, r13, wKS[13]);
        PKFMA(a2, r14, wKS[14]); PKFMA(a3, r15, wKS[15]);

        f32x2 s01 = a0 + a1;     // native pk_add (both halves valid)
        f32x2 s23 = a2 + a3;
        f32x2 sKS = s01 + s23;
        float K = sKS.x;
        float S = sKS.y;
#if HAVE_PLSWAP
        unsigned sv = __float_as_uint(S);
        auto rr = __builtin_amdgcn_permlane16_swap(sv, sv, false, false);
        float recv = takeX ? __uint_as_float((unsigned)rr[0])
                           : __uint_as_float((unsigned)rr[1]);
#else
        float recv = swz_x16(S);
#endif
        float u = (K + p) + recv;   // (K+p) issues while the swap is in flight
        h = fast_tanh_pre(u);
    };

#pragma unroll 1
    for (int e = 0; e < TT / 16; ++e) {
        const int tB = e * 16 + 8;
#pragma unroll
        for (int t = 0; t < 8; ++t)
            pB[t] = __bfloat162float(gp[(size_t)(tB + t) * PSTRIDE]);
#pragma unroll
        for (int t = 0; t < 8; ++t) PIN(pA[t]);
#pragma unroll
        for (int s = 0; s < 8; ++s) step(pA[s]);

        int tA = e * 16 + 16;
        if (tA > TT - 8) tA = TT - 8;
#pragma unroll
        for (int t = 0; t < 8; ++t)
            pA[t] = __bfloat162float(gp[(size_t)(tA + t) * PSTRIDE]);
#pragma unroll
        for (int t = 0; t < 8; ++t) PIN(pB[t]);
#pragma unroll
        for (int s = 0; s < 8; ++s) step(pB[s]);
    }

    __shared__ float hf[64];
    hf[l] = h;
    if (l < 10) {
        const int rr = l / 5, c = l % 5;
        float acc = b_cls[c];
#pragma unroll
        for (int k = 0; k < 32; ++k)
            acc = fmaf(hf[rr * 32 + k], W_cls[k * 5 + c], acc);
        out[(blockIdx.x * 2 + rr) * 5 + c] = acc;
    }
}

// ---------------- Fallback (fused) for tiny workspace ----------------------------------
__device__ __forceinline__ float rnn_step_fb(const float4 xt[8], const float wx[32],
                                             const float wh[32], float bj,
                                             float* hrow, int lane) {
    float u0 = 0.f, u1 = 0.f, u2 = 0.f, u3 = 0.f;
#pragma unroll
    for (int q = 0; q < 8; ++q) {
        u0 = fmaf(xt[q].x, wx[4*q+0], u0);
        u1 = fmaf(xt[q].y, wx[4*q+1], u1);
        u2 = fmaf(xt[q].z, wx[4*q+2], u2);
        u3 = fmaf(xt[q].w, wx[4*q+3], u3);
    }
    const float4* hp = (const float4*)hrow;
#pragma unroll
    for (int q = 0; q < 8; ++q) {
        float4 hv = hp[q];
        u0 = fmaf(hv.x, wh[4*q+0], u0);
        u1 = fmaf(hv.y, wh[4*q+1], u1);
        u2 = fmaf(hv.z, wh[4*q+2], u2);
        u3 = fmaf(hv.w, wh[4*q+3], u3);
    }
    float hn = fast_tanh(bj + ((u0 + u1) + (u2 + u3)));
    hrow[lane] = hn;
    return hn;
}

__global__ __launch_bounds__(64, 1) void rnn_seq_kernel(
        const int* __restrict__ x, const float* __restrict__ emb,
        const float* __restrict__ W_rnn, const float* __restrict__ b_rnn,
        const float* __restrict__ W_cls, const float* __restrict__ b_cls,
        float* __restrict__ out) {
    const int lane = threadIdx.x & 31;
    const int grp  = threadIdx.x >> 5;
    const int row  = blockIdx.x * 2 + grp;
    __shared__ float hbuf[2][HH];
    float wx[32], wh[32];
#pragma unroll
    for (int k = 0; k < 32; ++k) {
        wx[k] = W_rnn[k * HH + lane];
        wh[k] = W_rnn[(HH + k) * HH + lane];
    }
    const float bj = b_rnn[lane];
    hbuf[grp][lane] = 0.0f;
    float* hrow = &hbuf[grp][0];
    int i1 = x[1 * BB + row];
    float4 xcur[8], xnxt[8];
    {
        int i0 = x[0 * BB + row];
        const float4* ep = (const float4*)(emb + (size_t)i0 * HH);
#pragma unroll
        for (int q = 0; q < 8; ++q) xcur[q] = ep[q];
    }
    for (int t = 0; t < TT; t += 2) {
        int i2 = x[min(t + 2, TT - 1) * BB + row];
        {
            const float4* ep = (const float4*)(emb + (size_t)i1 * HH);
#pragma unroll
            for (int q = 0; q < 8; ++q) xnxt[q] = ep[q];
        }
        rnn_step_fb(xcur, wx, wh, bj, hrow, lane);
        i1 = x[min(t + 3, TT - 1) * BB + row];
        {
            const float4* ep = (const float4*)(emb + (size_t)i2 * HH);
#pragma unroll
            for (int q = 0; q < 8; ++q) xcur[q] = ep[q];
        }
        rnn_step_fb(xnxt, wx, wh, bj, hrow, lane);
    }
    if (lane < 5) {
        float acc = b_cls[lane];
#pragma unroll
        for (int k = 0; k < 32; ++k)
            acc = fmaf(hrow[k], W_cls[k * 5 + lane], acc);
        out[row * 5 + lane] = acc;
    }
}

extern "C" void kernel_launch(void* const* d_in, const int* in_sizes, int n_in,
                              void* d_out, int out_size, void* d_ws, size_t ws_size,
                              hipStream_t stream) {
    const int*   x     = (const int*)d_in[0];
    const float* emb   = (const float*)d_in[1];
    const float* W_rnn = (const float*)d_in[2];
    const float* b_rnn = (const float*)d_in[3];
    const float* W_cls = (const float*)d_in[4];
    const float* b_cls = (const float*)d_in[5];
    float* out = (float*)d_out;

    const size_t need16 = (size_t)NPAIR * HH * 2;   // 64 MiB (bf16 P)
    if (ws_size >= need16) {
        __hip_bfloat16* P = (__hip_bfloat16*)d_ws;
        const int pre_blocks = NPAIR / 256;         // 4096 blocks x 4 waves x 64 pairs
        precompute_mfma2<<<pre_blocks, 256, 0, stream>>>(x, emb, W_rnn, b_rnn, P);
        rnn_seq_v19<<<BB / 2, 64, 0, stream>>>(P, W_rnn, W_cls, b_cls, out);
    } else {
        rnn_seq_kernel<<<BB / 2, 64, 0, stream>>>(x, emb, W_rnn, b_rnn, W_cls, b_cls, out);
    }
}